// Round 2
// baseline (377.009 us; speedup 1.0000x reference)
//
#include <hip/hip_runtime.h>

// NewtonImplicitNet: z0 = x@W_in.T + b_in; 4x implicit blocks (fixed point of
// z = tanh(z@W.T + x), solved by Picard iteration — same fixed point as the
// reference's Newton, contraction factor ~0.5/iter); head GEMM + softmax.
// R1 -> R2: RPB 8->2 (1024 blocks = 4 blocks/CU co-resident; was 1/CU and
// barrier-stalled at 37% VALUBusy), NIT 32->20 (0.5^20 ~ 1e-6 residual,
// 30x margin to 7.8e-3 threshold), per-element reduce mapping.

#define B_ROWS  2048
#define D_IN    784
#define UNITS   128
#define D_OUT   10
#define RPB     2      // batch rows per block
#define THREADS 256
#define NIT     20     // Picard iterations per implicit block
#define KPAD    896    // 7 * 128, zero-padded D_IN

__device__ __forceinline__ float rcp_fast(float x) { return __builtin_amdgcn_rcpf(x); }

__device__ __forceinline__ float tanh_fast(float x) {
  // tanh(x) = 1 - 2/(e^{2x}+1); v_exp + v_rcp, ~1e-7 abs error, saturates correctly
  float e = __expf(2.0f * x);
  return 1.0f - 2.0f * rcp_fast(e + 1.0f);
}

__device__ __forceinline__ float4 f4fma(float a, const float4 b, float4 c) {
  c.x = fmaf(a, b.x, c.x);
  c.y = fmaf(a, b.y, c.y);
  c.z = fmaf(a, b.z, c.z);
  c.w = fmaf(a, b.w, c.w);
  return c;
}

union SmemU {
  float xb[RPB][KPAD];        // phase 0 only: staged x rows (7 KB)
  float P[8][RPB][UNITS];     // k-group partial sums (8 KB)
};

__global__ __launch_bounds__(THREADS) void fused_net(
    const float* __restrict__ x,
    const float* __restrict__ W_in,
    const float* __restrict__ b_in,
    const float* __restrict__ W1,
    const float* __restrict__ W2,
    const float* __restrict__ W3,
    const float* __restrict__ W4,
    const float* __restrict__ W_out,
    const float* __restrict__ b_out,
    float* __restrict__ out)
{
  __shared__ __align__(16) SmemU sh;
  __shared__ __align__(16) float zbuf[RPB][UNITS];   // current Picard iterate
  __shared__ __align__(16) float xfix[RPB][UNITS];   // block input (the "x" of the fixed point)
  __shared__ float lg[RPB][D_OUT];

  const int t  = threadIdx.x;
  const int ug = t & 31;          // unit group: covers u4..u4+3
  const int kg = t >> 5;          // k group: covers k0..k0+15
  const int u4 = ug * 4;
  const int k0 = kg * 16;
  const int r0 = blockIdx.x * RPB;
  // per-element mapping for reduce/tanh phases: every thread owns 1 element
  const int er = t >> 7;          // row 0..RPB-1
  const int eu = t & 127;         // unit 0..127

  // ---------------- stage x rows into LDS (zero-padded to KPAD) ----------------
  for (int idx = t; idx < RPB * (KPAD / 4); idx += THREADS) {
    int row = idx / (KPAD / 4);
    int c4  = idx % (KPAD / 4);
    int k   = c4 * 4;
    float4 v = make_float4(0.f, 0.f, 0.f, 0.f);
    const float* xr = x + (size_t)(r0 + row) * D_IN;
    if (k + 3 < D_IN) {
      v = *(const float4*)(xr + k);
    } else if (k < D_IN) {
      v.x = xr[k];
      if (k + 1 < D_IN) v.y = xr[k + 1];
      if (k + 2 < D_IN) v.z = xr[k + 2];
    }
    *(float4*)&sh.xb[row][k] = v;
  }
  __syncthreads();

  float4 p[RPB];
  float4 wreg[16];   // wreg[k'][j] = W[u4+j][k0+k'] — iteration-invariant slice

#pragma unroll
  for (int r = 0; r < RPB; ++r) p[r] = make_float4(0.f, 0.f, 0.f, 0.f);

  // ---------------- input GEMM: p += x @ W_in.T over 7 k-chunks of 128 ----------------
  for (int ch = 0; ch < 7; ++ch) {
    const int kbase = ch * 128 + k0;
#pragma unroll
    for (int m = 0; m < 4; ++m) {
      const int k = kbase + 4 * m;
      float aj[4][4];
#pragma unroll
      for (int j = 0; j < 4; ++j) {
        const float* wr = W_in + (size_t)(u4 + j) * D_IN;
        float4 v = make_float4(0.f, 0.f, 0.f, 0.f);
        if (k + 3 < D_IN) {
          v = *(const float4*)(wr + k);
        } else {
          if (k     < D_IN) v.x = wr[k];
          if (k + 1 < D_IN) v.y = wr[k + 1];
          if (k + 2 < D_IN) v.z = wr[k + 2];
          if (k + 3 < D_IN) v.w = wr[k + 3];
        }
        aj[j][0] = v.x; aj[j][1] = v.y; aj[j][2] = v.z; aj[j][3] = v.w;
      }
#pragma unroll
      for (int i = 0; i < 4; ++i)
        wreg[4 * m + i] = make_float4(aj[0][i], aj[1][i], aj[2][i], aj[3][i]);
    }
#pragma unroll
    for (int r = 0; r < RPB; ++r) {
#pragma unroll
      for (int m = 0; m < 4; ++m) {
        float4 zq = *(const float4*)&sh.xb[r][kbase + 4 * m];
        p[r] = f4fma(zq.x, wreg[4 * m + 0], p[r]);
        p[r] = f4fma(zq.y, wreg[4 * m + 1], p[r]);
        p[r] = f4fma(zq.z, wreg[4 * m + 2], p[r]);
        p[r] = f4fma(zq.w, wreg[4 * m + 3], p[r]);
      }
    }
  }

  __syncthreads();   // all xb reads done; union region becomes P
#pragma unroll
  for (int r = 0; r < RPB; ++r)
    *(float4*)&sh.P[kg][r][u4] = p[r];
  __syncthreads();

  {
    float s = b_in[eu];
#pragma unroll
    for (int g = 0; g < 8; ++g)
      s += sh.P[g][er][eu];
    xfix[er][eu] = s;              // block-1 input
    zbuf[er][eu] = tanh_fast(s);   // z0 = tanh(x), same start as reference
  }
  __syncthreads();

  // ---------------- 4 implicit blocks ----------------
  const float* const Ws[4] = {W1, W2, W3, W4};

  for (int wb = 0; wb < 4; ++wb) {
    const float* __restrict__ W = Ws[wb];
    // load register-resident transposed W slice: wreg[k'][j] = W[u4+j][k0+k']
#pragma unroll
    for (int m = 0; m < 4; ++m) {
      float aj[4][4];
#pragma unroll
      for (int j = 0; j < 4; ++j) {
        float4 v = *(const float4*)(W + (size_t)(u4 + j) * UNITS + k0 + 4 * m);
        aj[j][0] = v.x; aj[j][1] = v.y; aj[j][2] = v.z; aj[j][3] = v.w;
      }
#pragma unroll
      for (int i = 0; i < 4; ++i)
        wreg[4 * m + i] = make_float4(aj[0][i], aj[1][i], aj[2][i], aj[3][i]);
    }

    for (int it = 0; it < NIT; ++it) {
      // partials: p[r] = sum over this thread's 16 k of z[r][k] * W[u4..u4+3][k]
#pragma unroll
      for (int r = 0; r < RPB; ++r) {
        float4 acc = make_float4(0.f, 0.f, 0.f, 0.f);
#pragma unroll
        for (int m = 0; m < 4; ++m) {
          float4 zq = *(const float4*)&zbuf[r][k0 + 4 * m];   // broadcast read
          acc = f4fma(zq.x, wreg[4 * m + 0], acc);
          acc = f4fma(zq.y, wreg[4 * m + 1], acc);
          acc = f4fma(zq.z, wreg[4 * m + 2], acc);
          acc = f4fma(zq.w, wreg[4 * m + 3], acc);
        }
        p[r] = acc;
      }
#pragma unroll
      for (int r = 0; r < RPB; ++r)
        *(float4*)&sh.P[kg][r][u4] = p[r];
      __syncthreads();

      // reduce 8 k-groups, add xfix, tanh, write back (1 element per thread)
      float s = xfix[er][eu];
#pragma unroll
      for (int g = 0; g < 8; ++g)
        s += sh.P[g][er][eu];
      zbuf[er][eu] = tanh_fast(s);
      __syncthreads();
    }

    if (wb < 3) {
      // next block's input is this block's output; z restarts at tanh(input)
      float zo = zbuf[er][eu];
      xfix[er][eu] = zo;
      zbuf[er][eu] = tanh_fast(zo);
      __syncthreads();
    }
  }

  // ---------------- head: logits + softmax ----------------
  if (t < RPB * D_OUT) {
    int r = t / D_OUT, c = t % D_OUT;
    float s = b_out[c];
    const float* wo = W_out + (size_t)c * UNITS;
#pragma unroll
    for (int u = 0; u < UNITS; u += 4) {
      float4 zq = *(const float4*)&zbuf[r][u];
      float4 wq = *(const float4*)(wo + u);
      s = fmaf(zq.x, wq.x, s);
      s = fmaf(zq.y, wq.y, s);
      s = fmaf(zq.z, wq.z, s);
      s = fmaf(zq.w, wq.w, s);
    }
    lg[r][c] = s;
  }
  __syncthreads();
  if (t < RPB) {
    float m = lg[t][0];
#pragma unroll
    for (int c = 1; c < D_OUT; ++c) m = fmaxf(m, lg[t][c]);
    float e[D_OUT];
    float sum = 0.f;
#pragma unroll
    for (int c = 0; c < D_OUT; ++c) {
      e[c] = __expf(lg[t][c] - m);
      sum += e[c];
    }
    float rs = rcp_fast(sum);
    float* orow = out + (size_t)(r0 + t) * D_OUT;
#pragma unroll
    for (int c = 0; c < D_OUT; ++c) orow[c] = e[c] * rs;
  }
}

extern "C" void kernel_launch(void* const* d_in, const int* in_sizes, int n_in,
                              void* d_out, int out_size, void* d_ws, size_t ws_size,
                              hipStream_t stream) {
  const float* x     = (const float*)d_in[0];
  const float* W_in  = (const float*)d_in[1];
  const float* b_in  = (const float*)d_in[2];
  const float* W1    = (const float*)d_in[3];
  const float* W2    = (const float*)d_in[4];
  const float* W3    = (const float*)d_in[5];
  const float* W4    = (const float*)d_in[6];
  const float* W_out = (const float*)d_in[7];
  const float* b_out = (const float*)d_in[8];
  float* outp = (float*)d_out;

  dim3 grid(B_ROWS / RPB);
  dim3 block(THREADS);
  hipLaunchKernelGGL(fused_net, grid, block, 0, stream,
                     x, W_in, b_in, W1, W2, W3, W4, W_out, b_out, outp);
}

// Round 3
// 201.552 us; speedup vs baseline: 1.8705x; 1.8705x over previous
//
#include <hip/hip_runtime.h>

// NewtonImplicitNet: z0 = x@W_in.T + b_in; 4x implicit blocks (fixed point of
// z = tanh(z@W.T + x), solved by Picard iteration — same fixed point as the
// reference's Newton); head GEMM + softmax.
// R2 -> R3: fix the spill catastrophe (R2: VGPR 256, 148 MB scratch writes).
//   - #pragma unroll 1 on ch/wb/it loops (R2's compiler unrolled ch x7)
//   - no per-element bounds checks: chunks 0..5 full, chunk 6 = kg==0 epilogue
//   - __launch_bounds__(256,4): hard cap 128 VGPR -> 4 blocks/CU co-resident

#define B_ROWS  2048
#define D_IN    784
#define UNITS   128
#define D_OUT   10
#define RPB     2      // batch rows per block -> 1024 blocks = 4 blocks/CU
#define THREADS 256
#define NIT     20     // Picard iterations per implicit block (0.6^20 ~ 4e-5)
#define KPAD    896    // 7 * 128, zero-padded D_IN

__device__ __forceinline__ float rcp_fast(float x) { return __builtin_amdgcn_rcpf(x); }

__device__ __forceinline__ float tanh_fast(float x) {
  // tanh(x) = 1 - 2/(e^{2x}+1); v_exp + v_rcp, ~1e-7 abs error, saturates correctly
  float e = __expf(2.0f * x);
  return 1.0f - 2.0f * rcp_fast(e + 1.0f);
}

__device__ __forceinline__ float4 f4fma(float a, const float4 b, float4 c) {
  c.x = fmaf(a, b.x, c.x);
  c.y = fmaf(a, b.y, c.y);
  c.z = fmaf(a, b.z, c.z);
  c.w = fmaf(a, b.w, c.w);
  return c;
}

union SmemU {
  float xb[RPB][KPAD];        // phase 0 only: staged x rows (7 KB)
  float P[8][RPB][UNITS];     // k-group partial sums (8 KB)
};

__global__ __launch_bounds__(THREADS, 4) void fused_net(
    const float* __restrict__ x,
    const float* __restrict__ W_in,
    const float* __restrict__ b_in,
    const float* __restrict__ W1,
    const float* __restrict__ W2,
    const float* __restrict__ W3,
    const float* __restrict__ W4,
    const float* __restrict__ W_out,
    const float* __restrict__ b_out,
    float* __restrict__ out)
{
  __shared__ __align__(16) SmemU sh;
  __shared__ __align__(16) float zbuf[RPB][UNITS];   // current Picard iterate
  __shared__ __align__(16) float xfix[RPB][UNITS];   // block input (the "x" of the fixed point)
  __shared__ float lg[RPB][D_OUT];

  const int t  = threadIdx.x;
  const int ug = t & 31;          // unit group: covers u4..u4+3
  const int kg = t >> 5;          // k group: covers k0..k0+15
  const int u4 = ug * 4;
  const int k0 = kg * 16;
  const int r0 = blockIdx.x * RPB;
  // per-element mapping for reduce/tanh phases: every thread owns 1 element
  const int er = t >> 7;          // row 0..RPB-1
  const int eu = t & 127;         // unit 0..127

  // ---------------- stage x rows into LDS (zero-padded to KPAD) ----------------
#pragma unroll 1
  for (int idx = t; idx < RPB * (KPAD / 4); idx += THREADS) {
    int row = idx / (KPAD / 4);
    int c4  = idx % (KPAD / 4);
    int k   = c4 * 4;
    float4 v = make_float4(0.f, 0.f, 0.f, 0.f);
    const float* xr = x + (size_t)(r0 + row) * D_IN;
    if (k + 3 < D_IN) {
      v = *(const float4*)(xr + k);
    } else if (k < D_IN) {
      v.x = xr[k];
      if (k + 1 < D_IN) v.y = xr[k + 1];
      if (k + 2 < D_IN) v.z = xr[k + 2];
    }
    *(float4*)&sh.xb[row][k] = v;
  }
  __syncthreads();

  float4 p[RPB];
  float4 wreg[16];   // wreg[k'][j] = W[u4+j][k0+k'] — iteration-invariant slice

#pragma unroll
  for (int r = 0; r < RPB; ++r) p[r] = make_float4(0.f, 0.f, 0.f, 0.f);

  // ---------------- input GEMM: p += x @ W_in.T ----------------
  // chunks 0..5: k = ch*128 + k0 + [0,16) all < 768 <= 784 -> full float4 loads
#pragma unroll 1
  for (int ch = 0; ch < 6; ++ch) {
    const int kbase = ch * 128 + k0;
#pragma unroll
    for (int m = 0; m < 4; ++m) {
      const int k = kbase + 4 * m;
      float4 vj[4];
#pragma unroll
      for (int j = 0; j < 4; ++j)
        vj[j] = *(const float4*)(W_in + (size_t)(u4 + j) * D_IN + k);
      wreg[4 * m + 0] = make_float4(vj[0].x, vj[1].x, vj[2].x, vj[3].x);
      wreg[4 * m + 1] = make_float4(vj[0].y, vj[1].y, vj[2].y, vj[3].y);
      wreg[4 * m + 2] = make_float4(vj[0].z, vj[1].z, vj[2].z, vj[3].z);
      wreg[4 * m + 3] = make_float4(vj[0].w, vj[1].w, vj[2].w, vj[3].w);
    }
#pragma unroll
    for (int r = 0; r < RPB; ++r) {
#pragma unroll
      for (int m = 0; m < 4; ++m) {
        float4 zq = *(const float4*)&sh.xb[r][kbase + 4 * m];
        p[r] = f4fma(zq.x, wreg[4 * m + 0], p[r]);
        p[r] = f4fma(zq.y, wreg[4 * m + 1], p[r]);
        p[r] = f4fma(zq.z, wreg[4 * m + 2], p[r]);
        p[r] = f4fma(zq.w, wreg[4 * m + 3], p[r]);
      }
    }
  }
  // chunk 6: only k = 768..783 are real (784 = 6*128 + 16) -> kg==0 only, full float4s
  if (kg == 0) {
    const int kbase = 768;
#pragma unroll
    for (int m = 0; m < 4; ++m) {
      const int k = kbase + 4 * m;
      float4 vj[4];
#pragma unroll
      for (int j = 0; j < 4; ++j)
        vj[j] = *(const float4*)(W_in + (size_t)(u4 + j) * D_IN + k);
      wreg[4 * m + 0] = make_float4(vj[0].x, vj[1].x, vj[2].x, vj[3].x);
      wreg[4 * m + 1] = make_float4(vj[0].y, vj[1].y, vj[2].y, vj[3].y);
      wreg[4 * m + 2] = make_float4(vj[0].z, vj[1].z, vj[2].z, vj[3].z);
      wreg[4 * m + 3] = make_float4(vj[0].w, vj[1].w, vj[2].w, vj[3].w);
    }
#pragma unroll
    for (int r = 0; r < RPB; ++r) {
#pragma unroll
      for (int m = 0; m < 4; ++m) {
        float4 zq = *(const float4*)&sh.xb[r][kbase + 4 * m];
        p[r] = f4fma(zq.x, wreg[4 * m + 0], p[r]);
        p[r] = f4fma(zq.y, wreg[4 * m + 1], p[r]);
        p[r] = f4fma(zq.z, wreg[4 * m + 2], p[r]);
        p[r] = f4fma(zq.w, wreg[4 * m + 3], p[r]);
      }
    }
  }

  __syncthreads();   // all xb reads done; union region becomes P
#pragma unroll
  for (int r = 0; r < RPB; ++r)
    *(float4*)&sh.P[kg][r][u4] = p[r];
  __syncthreads();

  {
    float s = b_in[eu];
#pragma unroll
    for (int g = 0; g < 8; ++g)
      s += sh.P[g][er][eu];
    xfix[er][eu] = s;              // block-1 input
    zbuf[er][eu] = tanh_fast(s);   // z0 = tanh(x), same start as reference
  }
  __syncthreads();

  // ---------------- 4 implicit blocks ----------------
  const float* const Ws[4] = {W1, W2, W3, W4};

#pragma unroll 1
  for (int wb = 0; wb < 4; ++wb) {
    const float* __restrict__ W = Ws[wb];
    // load register-resident transposed W slice: wreg[k'][j] = W[u4+j][k0+k']
#pragma unroll
    for (int m = 0; m < 4; ++m) {
      float4 vj[4];
#pragma unroll
      for (int j = 0; j < 4; ++j)
        vj[j] = *(const float4*)(W + (size_t)(u4 + j) * UNITS + k0 + 4 * m);
      wreg[4 * m + 0] = make_float4(vj[0].x, vj[1].x, vj[2].x, vj[3].x);
      wreg[4 * m + 1] = make_float4(vj[0].y, vj[1].y, vj[2].y, vj[3].y);
      wreg[4 * m + 2] = make_float4(vj[0].z, vj[1].z, vj[2].z, vj[3].z);
      wreg[4 * m + 3] = make_float4(vj[0].w, vj[1].w, vj[2].w, vj[3].w);
    }

#pragma unroll 1
    for (int it = 0; it < NIT; ++it) {
      // partials: p[r] = sum over this thread's 16 k of z[r][k] * W[u4..u4+3][k]
#pragma unroll
      for (int r = 0; r < RPB; ++r) {
        float4 acc = make_float4(0.f, 0.f, 0.f, 0.f);
#pragma unroll
        for (int m = 0; m < 4; ++m) {
          float4 zq = *(const float4*)&zbuf[r][k0 + 4 * m];   // broadcast read
          acc = f4fma(zq.x, wreg[4 * m + 0], acc);
          acc = f4fma(zq.y, wreg[4 * m + 1], acc);
          acc = f4fma(zq.z, wreg[4 * m + 2], acc);
          acc = f4fma(zq.w, wreg[4 * m + 3], acc);
        }
        p[r] = acc;
      }
#pragma unroll
      for (int r = 0; r < RPB; ++r)
        *(float4*)&sh.P[kg][r][u4] = p[r];
      __syncthreads();

      // reduce 8 k-groups, add xfix, tanh, write back (1 element per thread)
      float s = xfix[er][eu];
#pragma unroll
      for (int g = 0; g < 8; ++g)
        s += sh.P[g][er][eu];
      zbuf[er][eu] = tanh_fast(s);
      __syncthreads();
    }

    if (wb < 3) {
      // next block's input is this block's output; z restarts at tanh(input)
      float zo = zbuf[er][eu];
      xfix[er][eu] = zo;
      zbuf[er][eu] = tanh_fast(zo);
      __syncthreads();
    }
  }

  // ---------------- head: logits + softmax ----------------
  if (t < RPB * D_OUT) {
    int r = t / D_OUT, c = t % D_OUT;
    float s = b_out[c];
    const float* wo = W_out + (size_t)c * UNITS;
#pragma unroll
    for (int u = 0; u < UNITS; u += 4) {
      float4 zq = *(const float4*)&zbuf[r][u];
      float4 wq = *(const float4*)(wo + u);
      s = fmaf(zq.x, wq.x, s);
      s = fmaf(zq.y, wq.y, s);
      s = fmaf(zq.z, wq.z, s);
      s = fmaf(zq.w, wq.w, s);
    }
    lg[r][c] = s;
  }
  __syncthreads();
  if (t < RPB) {
    float m = lg[t][0];
#pragma unroll
    for (int c = 1; c < D_OUT; ++c) m = fmaxf(m, lg[t][c]);
    float e[D_OUT];
    float sum = 0.f;
#pragma unroll
    for (int c = 0; c < D_OUT; ++c) {
      e[c] = __expf(lg[t][c] - m);
      sum += e[c];
    }
    float rs = rcp_fast(sum);
    float* orow = out + (size_t)(r0 + t) * D_OUT;
#pragma unroll
    for (int c = 0; c < D_OUT; ++c) orow[c] = e[c] * rs;
  }
}

extern "C" void kernel_launch(void* const* d_in, const int* in_sizes, int n_in,
                              void* d_out, int out_size, void* d_ws, size_t ws_size,
                              hipStream_t stream) {
  const float* x     = (const float*)d_in[0];
  const float* W_in  = (const float*)d_in[1];
  const float* b_in  = (const float*)d_in[2];
  const float* W1    = (const float*)d_in[3];
  const float* W2    = (const float*)d_in[4];
  const float* W3    = (const float*)d_in[5];
  const float* W4    = (const float*)d_in[6];
  const float* W_out = (const float*)d_in[7];
  const float* b_out = (const float*)d_in[8];
  float* outp = (float*)d_out;

  dim3 grid(B_ROWS / RPB);
  dim3 block(THREADS);
  hipLaunchKernelGGL(fused_net, grid, block, 0, stream,
                     x, W_in, b_in, W1, W2, W3, W4, W_out, b_out, outp);
}

// Round 4
// 135.936 us; speedup vs baseline: 2.7734x; 1.4827x over previous
//
#include <hip/hip_runtime.h>

// NewtonImplicitNet via Picard iteration, MFMA edition.
// R3 -> R4: the scalar-VALU structure was LDS-pipe-bound (178 LDS cyc vs
// 320/4 VALU cyc per wave-iter; 4 SIMDs share one LDS pipe -> VALUBusy 37%).
// Restructure: 128 blocks x 4 waves x 16 rows, mfma_f32_16x16x32_f16.
// Wave w owns units [32w,32w+32) (2 N-tiles, W frags in 32 VGPRs).
// Per iter: 4 ds_read_b128 (Z f16 A-frags) + 8 mfma + 8 tanh + 8 ds_write_b16,
// double-buffered Z -> 1 barrier/iter. K-reduce lives inside the MFMA.
// Input GEMM: f16 hi/lo split (3 mfma terms) -> ~1e-5 error. Iteration GEMM
// plain f16 (error ~1e-4 on z*). Block output = f32 accumulator (never
// quantized), carried in registers (D-layout == C-layout) across blocks.

#define B_ROWS  2048
#define D_IN    784
#define UNITS   128
#define D_OUT   10
#define RPB     16
#define THREADS 256
#define NIT     20      // must be even (double-buffer parity at wb boundary)
#define ZSTR    136     // f16 Z row stride (128 + 8 pad -> bank rotate)
#define HSTR    132     // f32 head row stride

typedef _Float16 f16x8 __attribute__((ext_vector_type(8)));
typedef float    f32x4 __attribute__((ext_vector_type(4)));

__device__ __forceinline__ float rcp_fast(float x) { return __builtin_amdgcn_rcpf(x); }

__device__ __forceinline__ float tanh_fast(float x) {
  // tanh(x) = 1 - 2/(e^{2x}+1); saturates correctly for large |x|
  float e = __expf(2.0f * x);
  return 1.0f - 2.0f * rcp_fast(e + 1.0f);
}

__device__ __forceinline__ f16x8 cvt8(f32x4 a, f32x4 b) {
  f16x8 r;
  r[0] = (_Float16)a[0]; r[1] = (_Float16)a[1]; r[2] = (_Float16)a[2]; r[3] = (_Float16)a[3];
  r[4] = (_Float16)b[0]; r[5] = (_Float16)b[1]; r[6] = (_Float16)b[2]; r[7] = (_Float16)b[3];
  return r;
}
__device__ __forceinline__ f16x8 res8(f32x4 a, f32x4 b, f16x8 hi) {
  f16x8 r;
  r[0] = (_Float16)(a[0] - (float)hi[0]); r[1] = (_Float16)(a[1] - (float)hi[1]);
  r[2] = (_Float16)(a[2] - (float)hi[2]); r[3] = (_Float16)(a[3] - (float)hi[3]);
  r[4] = (_Float16)(b[0] - (float)hi[4]); r[5] = (_Float16)(b[1] - (float)hi[5]);
  r[6] = (_Float16)(b[2] - (float)hi[6]); r[7] = (_Float16)(b[3] - (float)hi[7]);
  return r;
}

#define MFMA(a, b, c) __builtin_amdgcn_mfma_f32_16x16x32_f16((a), (b), (c), 0, 0, 0)

__global__ __launch_bounds__(THREADS, 1) void fused_net(
    const float* __restrict__ x,
    const float* __restrict__ W_in,
    const float* __restrict__ b_in,
    const float* __restrict__ W1,
    const float* __restrict__ W2,
    const float* __restrict__ W3,
    const float* __restrict__ W4,
    const float* __restrict__ W_out,
    const float* __restrict__ b_out,
    float* __restrict__ out)
{
  __shared__ __align__(16) _Float16 Zb[2][RPB][ZSTR];  // double-buffered Picard iterate (f16)
  __shared__ __align__(16) float    Zh[RPB][HSTR];     // final z4 (f32) for the head

  const int t    = threadIdx.x;
  const int w    = t >> 6;          // wave 0..3, owns units [32w, 32w+32)
  const int l    = t & 63;
  const int lo16 = l & 15;          // MFMA 16-group: A row m / B col n / D col n
  const int quad = l >> 4;          // MFMA quad:     A/B k-group, D row-group
  const int u0   = w * 32;
  const int r0   = blockIdx.x * RPB;

  // D/C layout: lane holds rows m = quad*4+i (i=0..3), col n = lo16 (per tile).
  // A layout:   lane holds A[m=lo16][k = 32s + quad*8 + j], j=0..7.
  // B layout:   lane holds B[k = 32s + quad*8 + j][n=lo16] = Wrow[n][k...] (row-major reads).

  // ================= input GEMM: xf = x @ W_in.T + b_in (f16 hi/lo split) =================
  f32x4 acc0 = {0.f, 0.f, 0.f, 0.f};
  f32x4 acc1 = {0.f, 0.f, 0.f, 0.f};
  const float* xrow  = x    + (size_t)(r0 + lo16) * D_IN;
  const float* w0row = W_in + (size_t)(u0 + lo16) * D_IN;
  const float* w1row = W_in + (size_t)(u0 + 16 + lo16) * D_IN;

#pragma unroll 1
  for (int s = 0; s < 25; ++s) {                 // 25 chunks of 32 cover 784 (+16 pad)
    const int k = s * 32 + quad * 8;
    const bool v = (k + 7) < D_IN;               // full-8 valid or fully zero
    f32x4 za = {0.f, 0.f, 0.f, 0.f}, zb = za;
    f32x4 xa = v ? *(const f32x4*)(xrow + k) : za;
    f32x4 xb = v ? *(const f32x4*)(xrow + k + 4) : zb;
    f32x4 aa = v ? *(const f32x4*)(w0row + k) : za;
    f32x4 ab = v ? *(const f32x4*)(w0row + k + 4) : zb;
    f32x4 ba = v ? *(const f32x4*)(w1row + k) : za;
    f32x4 bb = v ? *(const f32x4*)(w1row + k + 4) : zb;
    f16x8 ahi = cvt8(xa, xb);
    f16x8 alo = res8(xa, xb, ahi);
    f16x8 b0h = cvt8(aa, ab);
    f16x8 b0l = res8(aa, ab, b0h);
    f16x8 b1h = cvt8(ba, bb);
    f16x8 b1l = res8(ba, bb, b1h);
    acc0 = MFMA(ahi, b0h, acc0);
    acc0 = MFMA(ahi, b0l, acc0);
    acc0 = MFMA(alo, b0h, acc0);
    acc1 = MFMA(ahi, b1h, acc1);
    acc1 = MFMA(ahi, b1l, acc1);
    acc1 = MFMA(alo, b1h, acc1);
  }
  f32x4 xf0, xf1;   // fixed-point input for the current implicit block (f32, D-layout)
  {
    float b0 = b_in[u0 + lo16];
    float b1 = b_in[u0 + 16 + lo16];
#pragma unroll
    for (int i = 0; i < 4; ++i) { xf0[i] = acc0[i] + b0; xf1[i] = acc1[i] + b1; }
  }

  // ================= 4 implicit blocks: z = tanh(z @ W.T + xf), Picard =================
  const float* const Ws[4] = {W1, W2, W3, W4};

#pragma unroll 1
  for (int wb = 0; wb < 4; ++wb) {
    // W frags (f16, register-resident): wf[tile][s] = W[u][32s+quad*8 ..+7], u = u0+16*tile+lo16
    f16x8 wf[2][4];
    {
      const float* Wr0 = Ws[wb] + (size_t)(u0 + lo16) * UNITS;
      const float* Wr1 = Ws[wb] + (size_t)(u0 + 16 + lo16) * UNITS;
#pragma unroll
      for (int s = 0; s < 4; ++s) {
        const int k = s * 32 + quad * 8;
        wf[0][s] = cvt8(*(const f32x4*)(Wr0 + k), *(const f32x4*)(Wr0 + k + 4));
        wf[1][s] = cvt8(*(const f32x4*)(Wr1 + k), *(const f32x4*)(Wr1 + k + 4));
      }
    }

    // z0 = tanh(xf) into buffer 0 (scattered b16 writes: row m=quad*4+i, col u)
#pragma unroll
    for (int i = 0; i < 4; ++i) {
      Zb[0][quad * 4 + i][u0 + lo16]      = (_Float16)tanh_fast(xf0[i]);
      Zb[0][quad * 4 + i][u0 + 16 + lo16] = (_Float16)tanh_fast(xf1[i]);
    }
    __syncthreads();

    int p = 0;
#pragma unroll 1
    for (int it = 0; it < NIT; ++it) {
      // A-frags: Z[m=lo16][32s + quad*8 ..+7], one b128 per K-step, shared by both N-tiles
      f16x8 a0 = *(const f16x8*)&Zb[p][lo16][quad * 8];
      f16x8 a1 = *(const f16x8*)&Zb[p][lo16][32 + quad * 8];
      f16x8 a2 = *(const f16x8*)&Zb[p][lo16][64 + quad * 8];
      f16x8 a3 = *(const f16x8*)&Zb[p][lo16][96 + quad * 8];
      f32x4 c0 = xf0;   // C = xf: the "+x" of the fixed point, free via the accumulator
      f32x4 c1 = xf1;
      c0 = MFMA(a0, wf[0][0], c0);
      c1 = MFMA(a0, wf[1][0], c1);
      c0 = MFMA(a1, wf[0][1], c0);
      c1 = MFMA(a1, wf[1][1], c1);
      c0 = MFMA(a2, wf[0][2], c0);
      c1 = MFMA(a2, wf[1][2], c1);
      c0 = MFMA(a3, wf[0][3], c0);
      c1 = MFMA(a3, wf[1][3], c1);
      if (it == NIT - 1) {
        // last iterate = block output tanh(z@W.T+xf), kept f32 in regs -> next xf
#pragma unroll
        for (int i = 0; i < 4; ++i) { xf0[i] = tanh_fast(c0[i]); xf1[i] = tanh_fast(c1[i]); }
        // no write / no barrier: reads were from buf p = (NIT-1)&1 = 1; next wb
        // inits buf 0 (disjoint), then barriers before reading it.
      } else {
        const int q = p ^ 1;
#pragma unroll
        for (int i = 0; i < 4; ++i) {
          Zb[q][quad * 4 + i][u0 + lo16]      = (_Float16)tanh_fast(c0[i]);
          Zb[q][quad * 4 + i][u0 + 16 + lo16] = (_Float16)tanh_fast(c1[i]);
        }
        __syncthreads();
        p = q;
      }
    }
  }

  // ================= head: logits = z4 @ W_out.T + b_out, softmax =================
#pragma unroll
  for (int i = 0; i < 4; ++i) {
    Zh[quad * 4 + i][u0 + lo16]      = xf0[i];
    Zh[quad * 4 + i][u0 + 16 + lo16] = xf1[i];
  }
  __syncthreads();

  {
    const int hr = t >> 4;        // row 0..15
    const int hc = t & 15;        // col 0..15 (10 active)
    float lg = -1e30f;
    if (hc < D_OUT) {
      lg = b_out[hc];
      const float* wo = W_out + (size_t)hc * UNITS;
#pragma unroll 1
      for (int k = 0; k < UNITS; k += 4) {
        f32x4 zv = *(const f32x4*)&Zh[hr][k];
        f32x4 wv = *(const f32x4*)(wo + k);
        lg = fmaf(zv[0], wv[0], lg);
        lg = fmaf(zv[1], wv[1], lg);
        lg = fmaf(zv[2], wv[2], lg);
        lg = fmaf(zv[3], wv[3], lg);
      }
    }
    float mx = lg;
#pragma unroll
    for (int d = 1; d < 16; d <<= 1) mx = fmaxf(mx, __shfl_xor(mx, d, 16));
    float ex = (hc < D_OUT) ? __expf(lg - mx) : 0.f;
    float sm = ex;
#pragma unroll
    for (int d = 1; d < 16; d <<= 1) sm += __shfl_xor(sm, d, 16);
    if (hc < D_OUT)
      out[(size_t)(r0 + hr) * D_OUT + hc] = ex * rcp_fast(sm);
  }
}

extern "C" void kernel_launch(void* const* d_in, const int* in_sizes, int n_in,
                              void* d_out, int out_size, void* d_ws, size_t ws_size,
                              hipStream_t stream) {
  const float* x     = (const float*)d_in[0];
  const float* W_in  = (const float*)d_in[1];
  const float* b_in  = (const float*)d_in[2];
  const float* W1    = (const float*)d_in[3];
  const float* W2    = (const float*)d_in[4];
  const float* W3    = (const float*)d_in[5];
  const float* W4    = (const float*)d_in[6];
  const float* W_out = (const float*)d_in[7];
  const float* b_out = (const float*)d_in[8];
  float* outp = (float*)d_out;

  dim3 grid(B_ROWS / RPB);      // 128 blocks, 1 per CU, latency-optimized
  dim3 block(THREADS);
  hipLaunchKernelGGL(fused_net, grid, block, 0, stream,
                     x, W_in, b_in, W1, W2, W3, W4, W_out, b_out, outp);
}